// Round 5
// baseline (2929.425 us; speedup 1.0000x reference)
//
#include <hip/hip_runtime.h>
#include <hip/hip_bf16.h>

#define B_   64
#define T_   512
#define E_   300
#define U_   512
#define G4_  2048
#define D1_  1024
#define D2_  1024
#define NC_  20
#define KP_  320          // E_ padded to multiple of 32 for MFMA

typedef __bf16 bf16x8 __attribute__((ext_vector_type(8)));
typedef float  f32x4  __attribute__((ext_vector_type(4)));

__device__ __forceinline__ float sigmoidf_(float x) { return 1.0f / (1.0f + __expf(-x)); }

__device__ __forceinline__ void gl_lds16(const void* g, void* l) {
    __builtin_amdgcn_global_load_lds(
        (const __attribute__((address_space(1))) unsigned int*)g,
        (__attribute__((address_space(3))) unsigned int*)l, 16, 0, 0);
}

// ---------------------------------------------------------------------------
// init: zero parity-0 h chunks (4 groups x 2048 chunks x 16B) -> tag 0, h = 0
// ---------------------------------------------------------------------------
__global__ void init_kernel(uint4* __restrict__ hch) {
    int idx = blockIdx.x * 256 + threadIdx.x;      // 32 blocks -> 8192 chunks
    int g = idx >> 11, j = idx & 2047;
    hch[(size_t)g * 4096 + j] = (uint4){0u, 0u, 0u, 0u};
}

// ---------------------------------------------------------------------------
// prep: Wx (300x2048 f32) -> WxT[2048][320] bf16 (transposed, K zero-padded)
// ---------------------------------------------------------------------------
__global__ __launch_bounds__(256) void prep_wxT(const float* __restrict__ Wx,
                                                __hip_bfloat16* __restrict__ wxT) {
    __shared__ __hip_bfloat16 t[64][65];
    const int n0 = blockIdx.x * 64;   // 32 tiles
    const int k0 = blockIdx.y * 64;   // 5 tiles
    const int tid = threadIdx.x;
    for (int i = tid; i < 4096; i += 256) {
        int r = i >> 6, c = i & 63;
        int k = k0 + r;
        float v = (k < E_) ? Wx[(size_t)k * G4_ + n0 + c] : 0.f;
        t[r][c] = __float2bfloat16(v);
    }
    __syncthreads();
    for (int i = tid; i < 4096; i += 256) {
        int r = i >> 6, c = i & 63;
        wxT[(size_t)(n0 + r) * KP_ + k0 + c] = t[c][r];
    }
}

// ---------------------------------------------------------------------------
// prep: gather + cvt  xb[bt][k] = bf16(emb[tokens[bt]][k]), zero-padded K
// ---------------------------------------------------------------------------
__global__ __launch_bounds__(256) void prep_xb(const int* __restrict__ tokens,
                                               const float* __restrict__ emb,
                                               __hip_bfloat16* __restrict__ xb) {
    const int row = blockIdx.x * 4 + (threadIdx.x >> 6);
    const int ln  = threadIdx.x & 63;
    const int tok = tokens[row];
    const float* src = emb + (size_t)tok * E_;
    __hip_bfloat16* dst = xb + (size_t)row * KP_;
    for (int k = ln; k < KP_; k += 64)
        dst[k] = (k < E_) ? __float2bfloat16(src[k]) : __float2bfloat16(0.f);
}

// ---------------------------------------------------------------------------
// xg GEMM (MFMA): xg[t][b][n] = xb[bt] @ WxT^T + bias   (m97-style 128x128)
// ---------------------------------------------------------------------------
__global__ __launch_bounds__(256) void xg_gemm(const __hip_bfloat16* __restrict__ xb,
                                               const __hip_bfloat16* __restrict__ wxT,
                                               const float* __restrict__ bias,
                                               __hip_bfloat16* __restrict__ xg) {
    const int n0g = blockIdx.x * 128;   // 16
    const int bt0 = blockIdx.y * 128;   // 256
    const int tid = threadIdx.x;
    const int w   = tid >> 6;
    const int ln  = tid & 63;
    const int fn  = ln & 15;
    const int quad = ln >> 4;
    const int m0  = (w >> 1) * 64;
    const int n0w = (w & 1) * 64;

    __shared__ __align__(16) __hip_bfloat16 As[128 * 32];
    __shared__ __align__(16) __hip_bfloat16 Bs[128 * 32];

    f32x4 acc[4][4];
    #pragma unroll
    for (int im = 0; im < 4; ++im)
        #pragma unroll
        for (int in = 0; in < 4; ++in)
            acc[im][in] = (f32x4){0.f, 0.f, 0.f, 0.f};

    const __hip_bfloat16* ga = xb  + (size_t)(bt0 + w * 32 + (ln >> 2)) * KP_ + (ln & 3) * 8;
    const __hip_bfloat16* gb = wxT + (size_t)(n0g + w * 32 + (ln >> 2)) * KP_ + (ln & 3) * 8;

    for (int kt = 0; kt < KP_ / 32; ++kt) {
        gl_lds16(ga,             &As[(w * 32) * 32]);
        gl_lds16(ga + 16 * KP_,  &As[(w * 32 + 16) * 32]);
        gl_lds16(gb,             &Bs[(w * 32) * 32]);
        gl_lds16(gb + 16 * KP_,  &Bs[(w * 32 + 16) * 32]);
        ga += 32; gb += 32;
        __syncthreads();

        bf16x8 af[4], bfr[4];
        #pragma unroll
        for (int im = 0; im < 4; ++im)
            af[im] = *(const bf16x8*)&As[(m0 + im * 16 + fn) * 32 + quad * 8];
        #pragma unroll
        for (int in = 0; in < 4; ++in)
            bfr[in] = *(const bf16x8*)&Bs[(n0w + in * 16 + fn) * 32 + quad * 8];
        #pragma unroll
        for (int im = 0; im < 4; ++im)
            #pragma unroll
            for (int in = 0; in < 4; ++in)
                acc[im][in] = __builtin_amdgcn_mfma_f32_16x16x32_bf16(
                    af[im], bfr[in], acc[im][in], 0, 0, 0);
        __syncthreads();
    }

    #pragma unroll
    for (int in = 0; in < 4; ++in) {
        const int n = n0g + n0w + in * 16 + fn;
        const float bv = bias[n];
        #pragma unroll
        for (int im = 0; im < 4; ++im) {
            #pragma unroll
            for (int r = 0; r < 4; ++r) {
                int m = bt0 + m0 + im * 16 + quad * 4 + r;   // bt = b*T + t
                int bb = m >> 9, tt = m & 511;
                xg[(size_t)(tt * B_ + bb) * G4_ + n] =
                    __float2bfloat16(acc[im][in][r] + bv);
            }
        }
    }
}

// ---------------------------------------------------------------------------
// LSTM: 256 blocks = 64 unit-slices x 4 batch-groups; weight-stationary.
// Exchange: self-validating 8B halves {2x bf16 h, tag} stored coherently
// (RELAXED/AGENT atomic store -> per-store coherent dwordx2, no wbl2).
// Producers fire-and-forget; consumers poll the payload directly ->
// ONE cache round-trip per step (no flags, no producer ack-wait).
// ---------------------------------------------------------------------------
__global__ __launch_bounds__(256) void lstm_kernel(const __hip_bfloat16* __restrict__ xg,
                                                   const int* __restrict__ tokens,
                                                   const float* __restrict__ Wh,
                                                   uint4* __restrict__ hch,
                                                   __hip_bfloat16* __restrict__ hfin) {
    const int tid  = threadIdx.x;
    const int lane = tid & 63;
    const int wave = tid >> 6;
    const int x  = blockIdx.x & 7;
    const int r_ = blockIdx.x >> 3;
    const int ub = x * 8 + (r_ & 7);    // unit-slice: units [ub*8, ub*8+8)
    const int g  = r_ >> 3;             // batch-group: batches [g*16, g*16+16)
    const int u0 = ub * 8;

    __shared__ __align__(16) __hip_bfloat16 whsT[32][520];  // [c][k]
    __shared__ __align__(16) __hip_bfloat16 hs[16][520];    // [m][k]
    __shared__ float gbuf[16][32];
    __shared__ unsigned mask_lds[16][16];                   // token!=0 bitmask

    for (int idx = tid; idx < 32 * 512; idx += 256) {
        int c = idx & 31, k = idx >> 5;
        int col = ((c >> 3) << 9) + u0 + (c & 7);
        whsT[c][k] = __float2bfloat16(Wh[(size_t)k * G4_ + col]);
    }
    {
        int m = tid >> 4, wi = tid & 15;
        const int4* tp = (const int4*)(tokens + (size_t)(g * 16 + m) * T_ + wi * 32);
        unsigned bits = 0;
        #pragma unroll
        for (int q = 0; q < 8; ++q) {
            int4 v = tp[q];
            bits |= (v.x != 0 ? 1u : 0u) << (q * 4 + 0);
            bits |= (v.y != 0 ? 1u : 0u) << (q * 4 + 1);
            bits |= (v.z != 0 ? 1u : 0u) << (q * 4 + 2);
            bits |= (v.w != 0 ? 1u : 0u) << (q * 4 + 3);
        }
        mask_lds[m][wi] = bits;
    }

    // state: update threads tid<32 own 4 units each (one 16B chunk)
    float cst[4] = {0.f, 0.f, 0.f, 0.f};
    float hst[4] = {0.f, 0.f, 0.f, 0.f};
    const int um = tid >> 1;            // batch 0..15
    const int uu = (tid & 1) * 4;       // unit sub-offset 0/4

    // staging: thread -> (batch sm, chunks (tid&15) + 16*jj)
    const int sm  = tid >> 4;
    const int sjb = tid & 15;

    uint4* gbase = hch + (size_t)g * 4096;

    const int fn   = lane & 15;
    const int quad = lane >> 4;
    const int fc   = wave * 16 + fn;
    const int fcol = ((fc >> 3) << 9) + u0 + (fc & 7);

    __syncthreads();

    for (int s = 0; s < T_; ++s) {
        // xg prefetch (independent) — issues before the poll
        float xv[4];
        if (wave < 2) {
            #pragma unroll
            for (int r = 0; r < 4; ++r)
                xv[r] = __bfloat162float(
                    xg[(size_t)(s * B_ + g * 16 + quad * 4 + r) * G4_ + fcol]);
        }

        // stage h: poll tagged chunks (one LIC RT per retry round).
        // chunk layout: {h01, tag, h23, tag} — each 8B half atomic.
        {
            const uint4* cp = gbase + (s & 1) * 2048 + sm * 128 + sjb;
            uint4 v0, v1, v2, v3, v4, v5, v6, v7;
            const unsigned exp = (unsigned)s;
            for (;;) {
                asm volatile(
                    "global_load_dwordx4 %0, %8, off sc0 sc1\n\t"
                    "global_load_dwordx4 %1, %8, off offset:256 sc0 sc1\n\t"
                    "global_load_dwordx4 %2, %8, off offset:512 sc0 sc1\n\t"
                    "global_load_dwordx4 %3, %8, off offset:768 sc0 sc1\n\t"
                    "global_load_dwordx4 %4, %8, off offset:1024 sc0 sc1\n\t"
                    "global_load_dwordx4 %5, %8, off offset:1280 sc0 sc1\n\t"
                    "global_load_dwordx4 %6, %8, off offset:1536 sc0 sc1\n\t"
                    "global_load_dwordx4 %7, %8, off offset:1792 sc0 sc1\n\t"
                    "s_waitcnt vmcnt(0)"
                    : "=&v"(v0), "=&v"(v1), "=&v"(v2), "=&v"(v3),
                      "=&v"(v4), "=&v"(v5), "=&v"(v6), "=&v"(v7)
                    : "v"(cp)
                    : "memory");
                bool ok = (v0.y == exp) & (v0.w == exp) & (v1.y == exp) & (v1.w == exp)
                        & (v2.y == exp) & (v2.w == exp) & (v3.y == exp) & (v3.w == exp)
                        & (v4.y == exp) & (v4.w == exp) & (v5.y == exp) & (v5.w == exp)
                        & (v6.y == exp) & (v6.w == exp) & (v7.y == exp) & (v7.w == exp);
                if (ok) break;
                __builtin_amdgcn_s_sleep(1);
            }
            // hs[sm][chunk*4 ..] <- 4 bf16 (payload at .x/.z); chunks strided 16
            *(uint2*)&hs[sm][(sjb +   0) * 4] = (uint2){v0.x, v0.z};
            *(uint2*)&hs[sm][(sjb +  16) * 4] = (uint2){v1.x, v1.z};
            *(uint2*)&hs[sm][(sjb +  32) * 4] = (uint2){v2.x, v2.z};
            *(uint2*)&hs[sm][(sjb +  48) * 4] = (uint2){v3.x, v3.z};
            *(uint2*)&hs[sm][(sjb +  64) * 4] = (uint2){v4.x, v4.z};
            *(uint2*)&hs[sm][(sjb +  80) * 4] = (uint2){v5.x, v5.z};
            *(uint2*)&hs[sm][(sjb +  96) * 4] = (uint2){v6.x, v6.z};
            *(uint2*)&hs[sm][(sjb + 112) * 4] = (uint2){v7.x, v7.z};
        }
        __syncthreads();

        if (wave < 2) {
            f32x4 acc;
            #pragma unroll
            for (int r = 0; r < 4; ++r) acc[r] = xv[r];
            const __hip_bfloat16* arow = &hs[fn][quad * 8];
            const __hip_bfloat16* brow = &whsT[fc][quad * 8];
            #pragma unroll
            for (int kk = 0; kk < 16; ++kk) {
                bf16x8 av = *(const bf16x8*)(arow + kk * 32);
                bf16x8 bv = *(const bf16x8*)(brow + kk * 32);
                acc = __builtin_amdgcn_mfma_f32_16x16x32_bf16(av, bv, acc, 0, 0, 0);
            }
            #pragma unroll
            for (int r = 0; r < 4; ++r)
                gbuf[quad * 4 + r][fc] = acc[r];
        }
        __syncthreads();

        if (tid < 32) {
            const unsigned m = mask_lds[um][s >> 5] >> (s & 31) & 1u;
            #pragma unroll
            for (int q = 0; q < 4; ++q) {
                float gi = sigmoidf_(gbuf[um][uu + q]);
                float gf = sigmoidf_(gbuf[um][8 + uu + q]);
                float gc = gbuf[um][16 + uu + q];
                float go = sigmoidf_(gbuf[um][24 + uu + q]);
                float cn = gf * cst[q] + gi * fmaxf(gc, 0.f);
                float hn = go * fmaxf(cn, 0.f);
                if (m) { cst[q] = cn; hst[q] = hn; }
            }
            __hip_bfloat162 p0, p1;
            p0.x = __float2bfloat16(hst[0]); p0.y = __float2bfloat16(hst[1]);
            p1.x = __float2bfloat16(hst[2]); p1.y = __float2bfloat16(hst[3]);
            unsigned d0, d1;
            __builtin_memcpy(&d0, &p0, 4);
            __builtin_memcpy(&d1, &p1, 4);
            const unsigned long long tagw = (unsigned long long)(unsigned)(s + 1) << 32;
            unsigned long long h01 = tagw | d0;
            unsigned long long h23 = tagw | d1;
            unsigned long long* dst = (unsigned long long*)
                (gbase + ((s + 1) & 1) * 2048 + um * 128 + ub * 2 + (tid & 1));
            __hip_atomic_store(dst,     h01, __ATOMIC_RELAXED, __HIP_MEMORY_SCOPE_AGENT);
            __hip_atomic_store(dst + 1, h23, __ATOMIC_RELAXED, __HIP_MEMORY_SCOPE_AGENT);
            if (s == T_ - 1)
                *(uint2*)&hfin[(size_t)(g * 16 + um) * U_ + u0 + uu] = (uint2){d0, d1};
        }
        // no end barrier: next step's hs writes only happen after this step's
        // MFMA hs-reads (they precede sync #2) and gbuf reads precede sync #1
    }
}

// ---------------------------------------------------------------------------
// FC layers
// ---------------------------------------------------------------------------
__global__ __launch_bounds__(256) void fc1_kernel(const __hip_bfloat16* __restrict__ h,
                                                  const float* __restrict__ W,
                                                  const float* __restrict__ bias,
                                                  float* __restrict__ y) {
    int b = blockIdx.x >> 2, ch = blockIdx.x & 3;
    __shared__ float xrow[U_];
    for (int i = threadIdx.x; i < U_; i += 256)
        xrow[i] = __bfloat162float(h[b * U_ + i]);
    __syncthreads();
    int n = ch * 256 + threadIdx.x;
    float acc = 0.f;
    #pragma unroll 4
    for (int k = 0; k < U_; ++k) acc = fmaf(xrow[k], W[(size_t)k * D1_ + n], acc);
    y[b * D1_ + n] = fmaxf(acc + bias[n], 0.f);
}

__global__ __launch_bounds__(256) void fc2_kernel(const float* __restrict__ x,
                                                  const float* __restrict__ W,
                                                  const float* __restrict__ bias,
                                                  float* __restrict__ y) {
    int b = blockIdx.x >> 2, ch = blockIdx.x & 3;
    __shared__ float xrow[D1_];
    for (int i = threadIdx.x; i < D1_; i += 256) xrow[i] = x[b * D1_ + i];
    __syncthreads();
    int n = ch * 256 + threadIdx.x;
    float acc = 0.f;
    #pragma unroll 4
    for (int k = 0; k < D1_; ++k) acc = fmaf(xrow[k], W[(size_t)k * D2_ + n], acc);
    y[b * D2_ + n] = fmaxf(acc + bias[n], 0.f);
}

// ---------------------------------------------------------------------------
// logits + softmax
// ---------------------------------------------------------------------------
__global__ __launch_bounds__(64) void out_kernel(const float* __restrict__ h2,
                                                 const float* __restrict__ Wo,
                                                 const float* __restrict__ bo,
                                                 float* __restrict__ out) {
    int b = blockIdx.x;
    __shared__ float xrow[D2_];
    __shared__ float lg[NC_];
    __shared__ float red[2];
    for (int i = threadIdx.x; i < D2_; i += 64) xrow[i] = h2[b * D2_ + i];
    __syncthreads();
    if (threadIdx.x < NC_) {
        float a = bo[threadIdx.x];
        for (int k = 0; k < D2_; ++k) a = fmaf(xrow[k], Wo[k * NC_ + threadIdx.x], a);
        lg[threadIdx.x] = a;
    }
    __syncthreads();
    if (threadIdx.x == 0) {
        float mx = lg[0];
        for (int c = 1; c < NC_; ++c) mx = fmaxf(mx, lg[c]);
        float sm = 0.f;
        for (int c = 0; c < NC_; ++c) sm += expf(lg[c] - mx);
        red[0] = mx; red[1] = 1.0f / sm;
    }
    __syncthreads();
    if (threadIdx.x < NC_)
        out[b * NC_ + threadIdx.x] = expf(lg[threadIdx.x] - red[0]) * red[1];
}

// ---------------------------------------------------------------------------
extern "C" void kernel_launch(void* const* d_in, const int* in_sizes, int n_in,
                              void* d_out, int out_size, void* d_ws, size_t ws_size,
                              hipStream_t stream) {
    const int*   tokens = (const int*)d_in[0];
    const float* emb    = (const float*)d_in[1];
    const float* Wx     = (const float*)d_in[2];
    const float* Wh     = (const float*)d_in[3];
    const float* b      = (const float*)d_in[4];
    const float* W1     = (const float*)d_in[5];
    const float* b1     = (const float*)d_in[6];
    const float* W2     = (const float*)d_in[7];
    const float* b2     = (const float*)d_in[8];
    const float* Wo     = (const float*)d_in[9];
    const float* bo     = (const float*)d_in[10];
    float* out = (float*)d_out;

    char* ws = (char*)d_ws;
    const size_t XG_BYTES  = (size_t)T_ * B_ * G4_ * 2;        // 134,217,728
    const size_t CH_BYTES  = (size_t)4 * 2 * 2048 * 16;        // 262,144
    const size_t HF_BYTES  = (size_t)B_ * U_ * 2;              // 65,536
    __hip_bfloat16* xg   = (__hip_bfloat16*)ws;
    uint4* hch           = (uint4*)(ws + XG_BYTES);
    __hip_bfloat16* hfin = (__hip_bfloat16*)(ws + XG_BYTES + CH_BYTES);
    char* p = ws + XG_BYTES + CH_BYTES + HF_BYTES;
    float* h1            = (float*)p;                 p += (size_t)B_ * D1_ * 4;
    float* h2            = (float*)p;                 p += (size_t)B_ * D2_ * 4;
    __hip_bfloat16* xb   = (__hip_bfloat16*)p;        p += (size_t)B_ * T_ * KP_ * 2;
    __hip_bfloat16* wxT  = (__hip_bfloat16*)p;        // 2048*320*2 = 1.3 MB

    init_kernel<<<32, 256, 0, stream>>>(hch);
    prep_wxT<<<dim3(32, 5), 256, 0, stream>>>(Wx, wxT);
    prep_xb<<<(B_ * T_) / 4, 256, 0, stream>>>(tokens, emb, xb);
    xg_gemm<<<dim3(16, 256), 256, 0, stream>>>(xb, wxT, b, xg);
    lstm_kernel<<<256, 256, 0, stream>>>(xg, tokens, Wh, hch, hfin);
    fc1_kernel<<<256, 256, 0, stream>>>(hfin, W1, b1, h1);
    fc2_kernel<<<256, 256, 0, stream>>>(h1, W2, b2, h2);
    out_kernel<<<64, 64, 0, stream>>>(h2, Wo, bo, out);
}

// Round 6
// 1663.808 us; speedup vs baseline: 1.7607x; 1.7607x over previous
//
#include <hip/hip_runtime.h>
#include <hip/hip_bf16.h>

#define B_   64
#define T_   512
#define E_   300
#define U_   512
#define G4_  2048
#define D1_  1024
#define D2_  1024
#define NC_  20
#define KP_  320          // E_ padded to multiple of 32 for MFMA

// LSTM decomposition: 16 batch-groups (4 batches) x 16 unit-slices (32 units)
#define NBG_ 16
#define NUS_ 16
// dynamic LDS layout for lstm_kernel
#define WH_OFF   0
#define WH_BYTES (128 * 520 * 2)          // 133120: whsT[128][520] bf16
#define HS_OFF   (WH_OFF + WH_BYTES)
#define HS_BYTES (4 * 520 * 2)            // 4160:   hs[4][520] bf16
#define GB_OFF   (HS_OFF + HS_BYTES)
#define GB_BYTES (4 * 128 * 4)            // 2048:   gbuf[4][128] f32
#define MK_OFF   (GB_OFF + GB_BYTES)
#define MK_BYTES (4 * 16 * 4)             // 256:    masks[4][16]
#define SMEM_TOTAL (MK_OFF + MK_BYTES)    // 139584 <= 160 KiB

typedef __bf16 bf16x8 __attribute__((ext_vector_type(8)));
typedef float  f32x4  __attribute__((ext_vector_type(4)));

__device__ __forceinline__ float sigmoidf_(float x) { return 1.0f / (1.0f + __expf(-x)); }

__device__ __forceinline__ void gl_lds16(const void* g, void* l) {
    __builtin_amdgcn_global_load_lds(
        (const __attribute__((address_space(1))) unsigned int*)g,
        (__attribute__((address_space(3))) unsigned int*)l, 16, 0, 0);
}

// ---------------------------------------------------------------------------
// init: zero parity-0 chunks for all 16 bgroups (tag 0, h = 0)
// hch layout: [(bg*2 + parity)*512 + c], c = b*128 + ug   (16B chunks)
// ---------------------------------------------------------------------------
__global__ void init_kernel(uint4* __restrict__ hch) {
    int idx = blockIdx.x * 256 + threadIdx.x;      // 32 blocks -> 8192 chunks
    int bg = idx >> 9, c = idx & 511;
    hch[((size_t)bg * 2) * 512 + c] = (uint4){0u, 0u, 0u, 0u};
}

// ---------------------------------------------------------------------------
// prep: Wx (300x2048 f32) -> WxT[2048][320] bf16 (transposed, K zero-padded)
// ---------------------------------------------------------------------------
__global__ __launch_bounds__(256) void prep_wxT(const float* __restrict__ Wx,
                                                __hip_bfloat16* __restrict__ wxT) {
    __shared__ __hip_bfloat16 t[64][65];
    const int n0 = blockIdx.x * 64;   // 32 tiles
    const int k0 = blockIdx.y * 64;   // 5 tiles
    const int tid = threadIdx.x;
    for (int i = tid; i < 4096; i += 256) {
        int r = i >> 6, c = i & 63;
        int k = k0 + r;
        float v = (k < E_) ? Wx[(size_t)k * G4_ + n0 + c] : 0.f;
        t[r][c] = __float2bfloat16(v);
    }
    __syncthreads();
    for (int i = tid; i < 4096; i += 256) {
        int r = i >> 6, c = i & 63;
        wxT[(size_t)(n0 + r) * KP_ + k0 + c] = t[c][r];
    }
}

// ---------------------------------------------------------------------------
// prep: gather + cvt  xb[bt][k] = bf16(emb[tokens[bt]][k]), zero-padded K
// ---------------------------------------------------------------------------
__global__ __launch_bounds__(256) void prep_xb(const int* __restrict__ tokens,
                                               const float* __restrict__ emb,
                                               __hip_bfloat16* __restrict__ xb) {
    const int row = blockIdx.x * 4 + (threadIdx.x >> 6);
    const int ln  = threadIdx.x & 63;
    const int tok = tokens[row];
    const float* src = emb + (size_t)tok * E_;
    __hip_bfloat16* dst = xb + (size_t)row * KP_;
    for (int k = ln; k < KP_; k += 64)
        dst[k] = (k < E_) ? __float2bfloat16(src[k]) : __float2bfloat16(0.f);
}

// ---------------------------------------------------------------------------
// xg GEMM (MFMA): xg[t][b][n] = xb[bt] @ WxT^T + bias   (m97-style 128x128)
// ---------------------------------------------------------------------------
__global__ __launch_bounds__(256) void xg_gemm(const __hip_bfloat16* __restrict__ xb,
                                               const __hip_bfloat16* __restrict__ wxT,
                                               const float* __restrict__ bias,
                                               __hip_bfloat16* __restrict__ xg) {
    const int n0g = blockIdx.x * 128;   // 16
    const int bt0 = blockIdx.y * 128;   // 256
    const int tid = threadIdx.x;
    const int w   = tid >> 6;
    const int ln  = tid & 63;
    const int fn  = ln & 15;
    const int quad = ln >> 4;
    const int m0  = (w >> 1) * 64;
    const int n0w = (w & 1) * 64;

    __shared__ __align__(16) __hip_bfloat16 As[128 * 32];
    __shared__ __align__(16) __hip_bfloat16 Bs[128 * 32];

    f32x4 acc[4][4];
    #pragma unroll
    for (int im = 0; im < 4; ++im)
        #pragma unroll
        for (int in = 0; in < 4; ++in)
            acc[im][in] = (f32x4){0.f, 0.f, 0.f, 0.f};

    const __hip_bfloat16* ga = xb  + (size_t)(bt0 + w * 32 + (ln >> 2)) * KP_ + (ln & 3) * 8;
    const __hip_bfloat16* gb = wxT + (size_t)(n0g + w * 32 + (ln >> 2)) * KP_ + (ln & 3) * 8;

    for (int kt = 0; kt < KP_ / 32; ++kt) {
        gl_lds16(ga,             &As[(w * 32) * 32]);
        gl_lds16(ga + 16 * KP_,  &As[(w * 32 + 16) * 32]);
        gl_lds16(gb,             &Bs[(w * 32) * 32]);
        gl_lds16(gb + 16 * KP_,  &Bs[(w * 32 + 16) * 32]);
        ga += 32; gb += 32;
        __syncthreads();

        bf16x8 af[4], bfr[4];
        #pragma unroll
        for (int im = 0; im < 4; ++im)
            af[im] = *(const bf16x8*)&As[(m0 + im * 16 + fn) * 32 + quad * 8];
        #pragma unroll
        for (int in = 0; in < 4; ++in)
            bfr[in] = *(const bf16x8*)&Bs[(n0w + in * 16 + fn) * 32 + quad * 8];
        #pragma unroll
        for (int im = 0; im < 4; ++im)
            #pragma unroll
            for (int in = 0; in < 4; ++in)
                acc[im][in] = __builtin_amdgcn_mfma_f32_16x16x32_bf16(
                    af[im], bfr[in], acc[im][in], 0, 0, 0);
        __syncthreads();
    }

    #pragma unroll
    for (int in = 0; in < 4; ++in) {
        const int n = n0g + n0w + in * 16 + fn;
        const float bv = bias[n];
        #pragma unroll
        for (int im = 0; im < 4; ++im) {
            #pragma unroll
            for (int r = 0; r < 4; ++r) {
                int m = bt0 + m0 + im * 16 + quad * 4 + r;   // bt = b*T + t
                int bb = m >> 9, tt = m & 511;
                xg[(size_t)(tt * B_ + bb) * G4_ + n] =
                    __float2bfloat16(acc[im][in][r] + bv);
            }
        }
    }
}

// ---------------------------------------------------------------------------
// LSTM: 256 blocks = 16 bgroups (4 batches) x 16 uslices (32 units).
// Weight slice (128 gate-cols x 512) staged to LDS once, then held as MFMA
// B-fragments in REGISTERS for all 512 steps. Exchange: tagged 8B halves
// {2x bf16 h, tag} through coherent stores (RELAXED/AGENT); consumers poll
// payload with PER-CHUNK selective retry. 1 block/CU (big-LDS opt-in).
// ---------------------------------------------------------------------------
__global__ __launch_bounds__(256, 1) void lstm_kernel(const __hip_bfloat16* __restrict__ xg,
                                                      const int* __restrict__ tokens,
                                                      const float* __restrict__ Wh,
                                                      uint4* __restrict__ hch,
                                                      __hip_bfloat16* __restrict__ hfin) {
    extern __shared__ char smem[];
    __hip_bfloat16 (*whsT)[520] = (__hip_bfloat16(*)[520])(smem + WH_OFF);  // [lc][k]
    __hip_bfloat16 (*hs)[520]   = (__hip_bfloat16(*)[520])(smem + HS_OFF);  // [b][u]
    float (*gbuf)[128]          = (float(*)[128])(smem + GB_OFF);           // [b][lc]
    unsigned (*masks)[16]       = (unsigned(*)[16])(smem + MK_OFF);

    const int tid  = threadIdx.x;
    const int w    = tid >> 6;          // wave = gate index (0..3)
    const int lane = tid & 63;
    const int fn   = lane & 15;
    const int quad = lane >> 4;
    const int us   = blockIdx.x & 15;   // unit-slice: units [us*32, us*32+32)
    const int bg   = blockIdx.x >> 4;   // batch-group: batches [bg*4, bg*4+4)

    // stage Wh slice: whsT[lc][k] = Wh[k][gate*512 + us*32 + u], lc=gate*32+u
    for (int idx = tid; idx < 128 * 512; idx += 256) {
        int lc = idx & 127, k = idx >> 7;
        int gcol = ((lc >> 5) << 9) + us * 32 + (lc & 31);
        whsT[lc][k] = __float2bfloat16(Wh[(size_t)k * G4_ + gcol]);
    }
    // token!=0 bitmasks for the 4 batches
    if (tid < 64) {
        int b = tid >> 4, wi = tid & 15;
        const int4* tp = (const int4*)(tokens + (size_t)(bg * 4 + b) * T_ + wi * 32);
        unsigned bits = 0;
        #pragma unroll
        for (int q = 0; q < 8; ++q) {
            int4 v = tp[q];
            bits |= (v.x != 0 ? 1u : 0u) << (q * 4 + 0);
            bits |= (v.y != 0 ? 1u : 0u) << (q * 4 + 1);
            bits |= (v.z != 0 ? 1u : 0u) << (q * 4 + 2);
            bits |= (v.w != 0 ? 1u : 0u) << (q * 4 + 3);
        }
        masks[b][wi] = bits;
    }
    __syncthreads();

    // hoist weight fragments to registers (constant across all 512 steps)
    const int lc0 = w * 32 + fn;
    bf16x8 wfr0[16], wfr1[16];
    #pragma unroll
    for (int kk = 0; kk < 16; ++kk) {
        wfr0[kk] = *(const bf16x8*)&whsT[lc0][kk * 32 + quad * 8];
        wfr1[kk] = *(const bf16x8*)&whsT[lc0 + 16][kk * 32 + quad * 8];
    }

    // state: tid<32 -> batch b=tid>>3, unit-group j=tid&7 (units j*4..j*4+3)
    float cst[4] = {0.f, 0.f, 0.f, 0.f};
    float hst[4] = {0.f, 0.f, 0.f, 0.f};
    const int ub = tid >> 3;            // batch (update threads)
    const int uj = tid & 7;             // unit-group within slice

    for (int s = 0; s < T_; ++s) {
        // acc init from xg (normal L2 loads, issued before the poll)
        f32x4 acc0 = (f32x4){0.f, 0.f, 0.f, 0.f};
        f32x4 acc1 = (f32x4){0.f, 0.f, 0.f, 0.f};
        if (quad == 0) {
            const __hip_bfloat16* xp =
                xg + (size_t)(s * B_ + bg * 4) * G4_ + w * 512 + us * 32 + fn;
            #pragma unroll
            for (int r = 0; r < 4; ++r) {
                acc0[r] = __bfloat162float(xp[(size_t)r * G4_]);
                acc1[r] = __bfloat162float(xp[(size_t)r * G4_ + 16]);
            }
        }

        // stage h: 512 tagged chunks, 2 per thread; selective per-chunk retry
        {
            const uint4* cp = hch + ((size_t)bg * 2 + (s & 1)) * 512;
            const uint4* a0 = cp + tid;
            const uint4* a1 = cp + tid + 256;
            uint4 v0, v1;
            asm volatile(
                "global_load_dwordx4 %0, %2, off sc0 sc1\n\t"
                "global_load_dwordx4 %1, %3, off sc0 sc1\n\t"
                "s_waitcnt vmcnt(0)"
                : "=&v"(v0), "=&v"(v1) : "v"(a0), "v"(a1) : "memory");
            const unsigned exp = (unsigned)s;
            while (!((v0.y == exp) & (v0.w == exp))) {
                __builtin_amdgcn_s_sleep(1);
                asm volatile(
                    "global_load_dwordx4 %0, %1, off sc0 sc1\n\t"
                    "s_waitcnt vmcnt(0)"
                    : "=&v"(v0) : "v"(a0) : "memory");
            }
            while (!((v1.y == exp) & (v1.w == exp))) {
                __builtin_amdgcn_s_sleep(1);
                asm volatile(
                    "global_load_dwordx4 %0, %1, off sc0 sc1\n\t"
                    "s_waitcnt vmcnt(0)"
                    : "=&v"(v1) : "v"(a1) : "memory");
            }
            int c0 = tid, c1 = tid + 256;
            *(uint2*)&hs[c0 >> 7][(c0 & 127) * 4] = (uint2){v0.x, v0.z};
            *(uint2*)&hs[c1 >> 7][(c1 & 127) * 4] = (uint2){v1.x, v1.z};
        }
        __syncthreads();

        // GEMM: gates[b][lc] += h[b] @ Wh-slice ; A rows replicated (fn&3)
        #pragma unroll
        for (int kk = 0; kk < 16; ++kk) {
            bf16x8 afr = *(const bf16x8*)&hs[fn & 3][kk * 32 + quad * 8];
            acc0 = __builtin_amdgcn_mfma_f32_16x16x32_bf16(afr, wfr0[kk], acc0, 0, 0, 0);
            acc1 = __builtin_amdgcn_mfma_f32_16x16x32_bf16(afr, wfr1[kk], acc1, 0, 0, 0);
        }
        if (quad == 0) {
            #pragma unroll
            for (int r = 0; r < 4; ++r) {             // D row=quad*4+r -> batch r
                gbuf[r][lc0]      = acc0[r];
                gbuf[r][lc0 + 16] = acc1[r];
            }
        }
        __syncthreads();

        // update + fire-and-forget tagged store
        if (tid < 32) {
            const unsigned mk = masks[ub][s >> 5] >> (s & 31) & 1u;
            #pragma unroll
            for (int q = 0; q < 4; ++q) {
                int u = uj * 4 + q;
                float gi = sigmoidf_(gbuf[ub][u]);
                float gf = sigmoidf_(gbuf[ub][32 + u]);
                float gc = gbuf[ub][64 + u];
                float go = sigmoidf_(gbuf[ub][96 + u]);
                float cn = gf * cst[q] + gi * fmaxf(gc, 0.f);
                float hn = go * fmaxf(cn, 0.f);
                if (mk) { cst[q] = cn; hst[q] = hn; }
            }
            __hip_bfloat162 p0, p1;
            p0.x = __float2bfloat16(hst[0]); p0.y = __float2bfloat16(hst[1]);
            p1.x = __float2bfloat16(hst[2]); p1.y = __float2bfloat16(hst[3]);
            unsigned d0, d1;
            __builtin_memcpy(&d0, &p0, 4);
            __builtin_memcpy(&d1, &p1, 4);
            const unsigned long long tagw = (unsigned long long)(unsigned)(s + 1) << 32;
            unsigned long long* dst = (unsigned long long*)
                (hch + ((size_t)bg * 2 + ((s + 1) & 1)) * 512 + ub * 128 + us * 8 + uj);
            __hip_atomic_store(dst,     tagw | d0, __ATOMIC_RELAXED, __HIP_MEMORY_SCOPE_AGENT);
            __hip_atomic_store(dst + 1, tagw | d1, __ATOMIC_RELAXED, __HIP_MEMORY_SCOPE_AGENT);
            if (s == T_ - 1)
                *(uint2*)&hfin[(size_t)(bg * 4 + ub) * U_ + us * 32 + uj * 4] =
                    (uint2){d0, d1};
        }
        // no end barrier needed: hs(s+1) writes race only vs completed reads;
        // gbuf(s+1) writes occur after barrier#1(s+1) which waits for updaters
    }
}

// ---------------------------------------------------------------------------
// FC layers
// ---------------------------------------------------------------------------
__global__ __launch_bounds__(256) void fc1_kernel(const __hip_bfloat16* __restrict__ h,
                                                  const float* __restrict__ W,
                                                  const float* __restrict__ bias,
                                                  float* __restrict__ y) {
    int b = blockIdx.x >> 2, ch = blockIdx.x & 3;
    __shared__ float xrow[U_];
    for (int i = threadIdx.x; i < U_; i += 256)
        xrow[i] = __bfloat162float(h[b * U_ + i]);
    __syncthreads();
    int n = ch * 256 + threadIdx.x;
    float acc = 0.f;
    #pragma unroll 4
    for (int k = 0; k < U_; ++k) acc = fmaf(xrow[k], W[(size_t)k * D1_ + n], acc);
    y[b * D1_ + n] = fmaxf(acc + bias[n], 0.f);
}

__global__ __launch_bounds__(256) void fc2_kernel(const float* __restrict__ x,
                                                  const float* __restrict__ W,
                                                  const float* __restrict__ bias,
                                                  float* __restrict__ y) {
    int b = blockIdx.x >> 2, ch = blockIdx.x & 3;
    __shared__ float xrow[D1_];
    for (int i = threadIdx.x; i < D1_; i += 256) xrow[i] = x[b * D1_ + i];
    __syncthreads();
    int n = ch * 256 + threadIdx.x;
    float acc = 0.f;
    #pragma unroll 4
    for (int k = 0; k < D1_; ++k) acc = fmaf(xrow[k], W[(size_t)k * D2_ + n], acc);
    y[b * D2_ + n] = fmaxf(acc + bias[n], 0.f);
}

// ---------------------------------------------------------------------------
// logits + softmax
// ---------------------------------------------------------------------------
__global__ __launch_bounds__(64) void out_kernel(const float* __restrict__ h2,
                                                 const float* __restrict__ Wo,
                                                 const float* __restrict__ bo,
                                                 float* __restrict__ out) {
    int b = blockIdx.x;
    __shared__ float xrow[D2_];
    __shared__ float lg[NC_];
    __shared__ float red[2];
    for (int i = threadIdx.x; i < D2_; i += 64) xrow[i] = h2[b * D2_ + i];
    __syncthreads();
    if (threadIdx.x < NC_) {
        float a = bo[threadIdx.x];
        for (int k = 0; k < D2_; ++k) a = fmaf(xrow[k], Wo[k * NC_ + threadIdx.x], a);
        lg[threadIdx.x] = a;
    }
    __syncthreads();
    if (threadIdx.x == 0) {
        float mx = lg[0];
        for (int c = 1; c < NC_; ++c) mx = fmaxf(mx, lg[c]);
        float sm = 0.f;
        for (int c = 0; c < NC_; ++c) sm += expf(lg[c] - mx);
        red[0] = mx; red[1] = 1.0f / sm;
    }
    __syncthreads();
    if (threadIdx.x < NC_)
        out[b * NC_ + threadIdx.x] = expf(lg[threadIdx.x] - red[0]) * red[1];
}

// ---------------------------------------------------------------------------
extern "C" void kernel_launch(void* const* d_in, const int* in_sizes, int n_in,
                              void* d_out, int out_size, void* d_ws, size_t ws_size,
                              hipStream_t stream) {
    const int*   tokens = (const int*)d_in[0];
    const float* emb    = (const float*)d_in[1];
    const float* Wx     = (const float*)d_in[2];
    const float* Wh     = (const float*)d_in[3];
    const float* b      = (const float*)d_in[4];
    const float* W1     = (const float*)d_in[5];
    const float* b1     = (const float*)d_in[6];
    const float* W2     = (const float*)d_in[7];
    const float* b2     = (const float*)d_in[8];
    const float* Wo     = (const float*)d_in[9];
    const float* bo     = (const float*)d_in[10];
    float* out = (float*)d_out;

    char* ws = (char*)d_ws;
    const size_t XG_BYTES  = (size_t)T_ * B_ * G4_ * 2;        // 134,217,728
    const size_t CH_BYTES  = (size_t)NBG_ * 2 * 512 * 16;      // 262,144
    const size_t HF_BYTES  = (size_t)B_ * U_ * 2;              // 65,536
    __hip_bfloat16* xg   = (__hip_bfloat16*)ws;
    uint4* hch           = (uint4*)(ws + XG_BYTES);
    __hip_bfloat16* hfin = (__hip_bfloat16*)(ws + XG_BYTES + CH_BYTES);
    char* p = ws + XG_BYTES + CH_BYTES + HF_BYTES;
    float* h1            = (float*)p;                 p += (size_t)B_ * D1_ * 4;
    float* h2            = (float*)p;                 p += (size_t)B_ * D2_ * 4;
    __hip_bfloat16* xb   = (__hip_bfloat16*)p;        p += (size_t)B_ * T_ * KP_ * 2;
    __hip_bfloat16* wxT  = (__hip_bfloat16*)p;        // 2048*320*2 = 1.3 MB

    hipFuncSetAttribute((const void*)lstm_kernel,
                        hipFuncAttributeMaxDynamicSharedMemorySize, SMEM_TOTAL);

    init_kernel<<<32, 256, 0, stream>>>(hch);
    prep_wxT<<<dim3(32, 5), 256, 0, stream>>>(Wx, wxT);
    prep_xb<<<(B_ * T_) / 4, 256, 0, stream>>>(tokens, emb, xb);
    xg_gemm<<<dim3(16, 256), 256, 0, stream>>>(xb, wxT, b, xg);
    lstm_kernel<<<256, 256, SMEM_TOTAL, stream>>>(xg, tokens, Wh, hch, hfin);
    fc1_kernel<<<256, 256, 0, stream>>>(hfin, W1, b1, h1);
    fc2_kernel<<<256, 256, 0, stream>>>(h1, W2, b2, h2);
    out_kernel<<<64, 64, 0, stream>>>(h2, Wo, bo, out);
}